// Round 1
// baseline (499.434 us; speedup 1.0000x reference)
//
#include <hip/hip_runtime.h>

// Problem constants (from reference): B=2,T=4,V=4,H=128,W=128, NQ=64, QDIM=256, IDIM=32, MDIM=16
#define BT    8
#define VHW   (4*128*128)    // 65536 spatial per (b,t)
#define NQn   64
#define QD    256
#define ID    32
#define MD    16
#define CD    48             // ID+MD combined table

// Kernel A: project query_feat -> combined table qtab[bt][q][48] (first 32 inst, last 16 motion)
// d = idx>>9 is wave-uniform (all lanes share d) -> uniform branch, uniform W column.
__global__ __launch_bounds__(256) void qproj_kernel(
    const float* __restrict__ qf,   // [BT][64][256]
    const float* __restrict__ Wi,   // [256][32]
    const float* __restrict__ bi,   // [32]
    const float* __restrict__ Wm,   // [256][16]
    const float* __restrict__ bm,   // [16]
    float* __restrict__ qtab)       // [BT][64][48]
{
    int idx = blockIdx.x * 256 + threadIdx.x;   // 48 * 512 = 24576 threads
    int d   = idx >> 9;        // 0..47, uniform within wave
    int btq = idx & 511;       // 0..511
    const float* __restrict__ qrow = qf + btq * QD;
    float a;
    if (d < ID) {
        a = bi[d];
        #pragma unroll 8
        for (int k = 0; k < QD; ++k) a = fmaf(qrow[k], Wi[k*ID + d], a);
    } else {
        int dm = d - ID;
        a = bm[dm];
        #pragma unroll 8
        for (int k = 0; k < QD; ++k) a = fmaf(qrow[k], Wm[k*MD + dm], a);
    }
    qtab[btq * CD + d] = a;
}

// Kernel B: one thread per spatial location.
// bt = blockIdx.x >> 8 is scalar (block-uniform by construction: 256 blocks per bt),
// so qtab row addresses are uniform -> scalar loads / single-line broadcast loads.
__global__ __launch_bounds__(256) void entity_kernel(
    const float* __restrict__ ia,     // [BT*VHW][32]
    const float* __restrict__ mc,     // [BT*VHW][16]
    const float* __restrict__ ap,     // [BT*VHW][65]
    const int*   __restrict__ aq,     // [BT*VHW]
    const float* __restrict__ qtab,   // [BT][64][48]
    float* __restrict__ out_id,       // [BT*VHW] (as float)
    float* __restrict__ out_inst,     // [BT*VHW][32]
    float* __restrict__ out_mot)      // [BT*VHW][16]
{
    const int  bt  = blockIdx.x >> 8;                       // uniform
    const long loc = ((long)blockIdx.x << 8) + threadIdx.x; // < 524288
    const float* __restrict__ qt    = qtab + bt * (NQn * CD);
    const float* __restrict__ aprow = ap + loc * (NQn + 1);

    float acc[CD];
    #pragma unroll
    for (int d = 0; d < CD; ++d) acc[d] = 0.0f;

    const float bg = aprow[0];
    float psum = 0.0f;

    #pragma unroll 4
    for (int q = 0; q < NQn; ++q) {
        float p = aprow[1 + q];
        psum += p;
        const float* __restrict__ row = qt + q * CD;  // uniform address
        #pragma unroll
        for (int d = 0; d < CD; ++d) acc[d] = fmaf(p, row[d], acc[d]);
    }

    const float scale = (1.0f - bg) / fmaxf(psum, 1e-6f);

    // inst: 32 floats, 128B-aligned per location -> float4
    const float4* __restrict__ ia4 = (const float4*)(ia + loc * ID);
    float4* __restrict__ oi4 = (float4*)(out_inst + loc * ID);
    #pragma unroll
    for (int i = 0; i < ID/4; ++i) {
        float4 v = ia4[i];
        v.x = fmaf(scale, acc[4*i+0], v.x);
        v.y = fmaf(scale, acc[4*i+1], v.y);
        v.z = fmaf(scale, acc[4*i+2], v.z);
        v.w = fmaf(scale, acc[4*i+3], v.w);
        oi4[i] = v;
    }
    // motion: 16 floats, 64B-aligned -> float4
    const float4* __restrict__ mc4 = (const float4*)(mc + loc * MD);
    float4* __restrict__ om4 = (float4*)(out_mot + loc * MD);
    #pragma unroll
    for (int i = 0; i < MD/4; ++i) {
        float4 v = mc4[i];
        v.x = fmaf(scale, acc[ID+4*i+0], v.x);
        v.y = fmaf(scale, acc[ID+4*i+1], v.y);
        v.z = fmaf(scale, acc[ID+4*i+2], v.z);
        v.w = fmaf(scale, acc[ID+4*i+3], v.w);
        om4[i] = v;
    }

    out_id[loc] = (float)aq[loc];
}

extern "C" void kernel_launch(void* const* d_in, const int* in_sizes, int n_in,
                              void* d_out, int out_size, void* d_ws, size_t ws_size,
                              hipStream_t stream) {
    const float* ia = (const float*)d_in[0];   // instance_affinity
    const float* mc = (const float*)d_in[1];   // motion_code
    const float* qf = (const float*)d_in[2];   // query_feat
    const float* ap = (const float*)d_in[3];   // assignment_prob
    const int*   aq = (const int*)  d_in[4];   // assigned_query
    const float* Wi = (const float*)d_in[5];
    const float* bi = (const float*)d_in[6];
    const float* Wm = (const float*)d_in[7];
    const float* bm = (const float*)d_in[8];

    float* qtab = (float*)d_ws;                        // 8*64*48*4 = 98304 B

    float* out_id   = (float*)d_out;                   // 524288
    float* out_inst = out_id + (long)BT * VHW;         // 16777216
    float* out_mot  = out_inst + (long)BT * VHW * ID;  // 8388608

    qproj_kernel<<<(48 * 512) / 256, 256, 0, stream>>>(qf, Wi, bi, Wm, bm, qtab);
    entity_kernel<<<(BT * VHW) / 256, 256, 0, stream>>>(ia, mc, ap, aq, qtab,
                                                        out_id, out_inst, out_mot);
}

// Round 2
// 378.624 us; speedup vs baseline: 1.3191x; 1.3191x over previous
//
#include <hip/hip_runtime.h>

// Problem constants: B=2,T=4,V=4,H=128,W=128, NQ=64, QDIM=256, IDIM=32, MDIM=16
#define BT    8
#define VHW   (4*128*128)    // 65536 spatial per (b,t)
#define NQn   64
#define QD    256
#define ID    32
#define MD    16
#define CD    48             // ID+MD combined table
#define TILE  256            // locations per block

// Kernel A: project query_feat -> combined table qtab[bt][q][48].
// Mapping d-fast: lanes cover contiguous W columns (coalesced); qrow is
// near-uniform per wave (<=2 distinct rows -> L1 broadcast).
__global__ __launch_bounds__(256) void qproj_kernel(
    const float* __restrict__ qf,   // [BT*64][256]
    const float* __restrict__ Wi,   // [256][32]
    const float* __restrict__ bi,   // [32]
    const float* __restrict__ Wm,   // [256][16]
    const float* __restrict__ bm,   // [16]
    float* __restrict__ qtab)       // [BT*64][48]
{
    int idx = blockIdx.x * 256 + threadIdx.x;   // 512*48 = 24576 threads
    int btq = idx / CD;
    int d   = idx - btq * CD;      // 0..47, fast dim
    const float* __restrict__ qrow = qf + btq * QD;
    float a;
    if (d < ID) {
        a = bi[d];
        #pragma unroll 8
        for (int k = 0; k < QD; ++k) a = fmaf(qrow[k], Wi[k*ID + d], a);
    } else {
        int dm = d - ID;
        a = bm[dm];
        #pragma unroll 8
        for (int k = 0; k < QD; ++k) a = fmaf(qrow[k], Wm[k*MD + dm], a);
    }
    qtab[idx] = a;
}

// Kernel B: one thread per location; block's assignment_prob span (contiguous
// 256 rows x 65 floats = 66,560 B) staged through LDS with coalesced float4
// loads so each HBM line is fetched exactly once. Row stride 65 (odd) ->
// LDS bank = (t+q) mod 32 -> 2-way aliasing only (free).
__global__ __launch_bounds__(256) void entity_kernel(
    const float* __restrict__ ia,     // [BT*VHW][32]
    const float* __restrict__ mc,     // [BT*VHW][16]
    const float* __restrict__ ap,     // [BT*VHW][65]
    const int*   __restrict__ aq,     // [BT*VHW]
    const float* __restrict__ qtab,   // [BT][64][48]
    float* __restrict__ out_id,       // [BT*VHW] (as float)
    float* __restrict__ out_inst,     // [BT*VHW][32]
    float* __restrict__ out_mot)      // [BT*VHW][16]
{
    __shared__ float ap_s[TILE * (NQn + 1)];     // 66,560 B -> 2 blocks/CU

    const int  bt   = blockIdx.x >> 8;                    // uniform (256 blocks per bt)
    const long base = (long)blockIdx.x * TILE;
    const int  t    = threadIdx.x;

    // ---- stage ap tile: contiguous span, fully coalesced ----
    {
        const float4* __restrict__ src = (const float4*)(ap + base * (NQn + 1)); // 16B-aligned: 66,560 % 16 == 0
        float4* dst = (float4*)ap_s;
        #pragma unroll
        for (int f = t, k = 0; k < 17; ++k, f += 256)
            if (f < (TILE * (NQn + 1)) / 4) dst[f] = src[f];
    }
    __syncthreads();

    const long loc = base + t;
    const float* __restrict__ qt    = qtab + bt * (NQn * CD);   // uniform -> scalar loads
    const float* __restrict__ aprow = ap_s + t * (NQn + 1);

    float acc[CD];
    #pragma unroll
    for (int d = 0; d < CD; ++d) acc[d] = 0.0f;

    const float bg = aprow[0];
    float psum = 0.0f;

    #pragma unroll 4
    for (int q = 0; q < NQn; ++q) {
        float p = aprow[1 + q];
        psum += p;
        const float* __restrict__ row = qt + q * CD;
        #pragma unroll
        for (int d = 0; d < CD; ++d) acc[d] = fmaf(p, row[d], acc[d]);
    }

    const float scale = (1.0f - bg) / fmaxf(psum, 1e-6f);

    const float4* __restrict__ ia4 = (const float4*)(ia + loc * ID);
    float4* __restrict__ oi4 = (float4*)(out_inst + loc * ID);
    #pragma unroll
    for (int i = 0; i < ID/4; ++i) {
        float4 v = ia4[i];
        v.x = fmaf(scale, acc[4*i+0], v.x);
        v.y = fmaf(scale, acc[4*i+1], v.y);
        v.z = fmaf(scale, acc[4*i+2], v.z);
        v.w = fmaf(scale, acc[4*i+3], v.w);
        oi4[i] = v;
    }
    const float4* __restrict__ mc4 = (const float4*)(mc + loc * MD);
    float4* __restrict__ om4 = (float4*)(out_mot + loc * MD);
    #pragma unroll
    for (int i = 0; i < MD/4; ++i) {
        float4 v = mc4[i];
        v.x = fmaf(scale, acc[ID+4*i+0], v.x);
        v.y = fmaf(scale, acc[ID+4*i+1], v.y);
        v.z = fmaf(scale, acc[ID+4*i+2], v.z);
        v.w = fmaf(scale, acc[ID+4*i+3], v.w);
        om4[i] = v;
    }

    out_id[loc] = (float)aq[loc];
}

extern "C" void kernel_launch(void* const* d_in, const int* in_sizes, int n_in,
                              void* d_out, int out_size, void* d_ws, size_t ws_size,
                              hipStream_t stream) {
    const float* ia = (const float*)d_in[0];   // instance_affinity
    const float* mc = (const float*)d_in[1];   // motion_code
    const float* qf = (const float*)d_in[2];   // query_feat
    const float* ap = (const float*)d_in[3];   // assignment_prob
    const int*   aq = (const int*)  d_in[4];   // assigned_query
    const float* Wi = (const float*)d_in[5];
    const float* bi = (const float*)d_in[6];
    const float* Wm = (const float*)d_in[7];
    const float* bm = (const float*)d_in[8];

    float* qtab = (float*)d_ws;                        // 8*64*48*4 = 98,304 B

    float* out_id   = (float*)d_out;                   // 524288
    float* out_inst = out_id + (long)BT * VHW;         // 16,777,216
    float* out_mot  = out_inst + (long)BT * VHW * ID;  // 8,388,608

    qproj_kernel<<<(BT * NQn * CD) / 256, 256, 0, stream>>>(qf, Wi, bi, Wm, bm, qtab);
    entity_kernel<<<(BT * VHW) / TILE, TILE, 0, stream>>>(ia, mc, ap, aq, qtab,
                                                          out_id, out_inst, out_mot);
}

// Round 3
// 343.127 us; speedup vs baseline: 1.4555x; 1.1035x over previous
//
#include <hip/hip_runtime.h>

// B=2,T=4,V=4,H=128,W=128, NQ=64, QDIM=256, IDIM=32, MDIM=16
#define BT    8
#define VHW   (4*128*128)
#define NQn   64
#define QD    256
#define ID    32
#define MD    16
#define CD    48
#define APW   65          // assignment_prob row width (bg + 64 fg)
#define PITCH 72          // LDS bf16 row pitch: 144 B = 16B-aligned, 4-bank shift/row

typedef short bf16x8 __attribute__((ext_vector_type(8)));
typedef float f32x4  __attribute__((ext_vector_type(4)));

// fp32 -> bf16 RNE, independent of __hip_bfloat16 internals
static __device__ __forceinline__ short f2bf(float f) {
    unsigned u = __builtin_bit_cast(unsigned, f);
    unsigned r = (u + 0x7FFFu + ((u >> 16) & 1u)) >> 16;
    return (short)r;
}

// Kernel A: project query_feat -> bf16 table PRE-PACKED in MFMA B-fragment layout:
// qtabB[bt][ntile 0..2][ktile 0..1][lane 0..63][j 0..7], where for 16x16x32 bf16
// B-frag: n = lane&15, k = (lane>>4)*8 + j. Global d = ntile*16+n, q = ktile*32+k.
__global__ __launch_bounds__(256) void qproj_kernel(
    const float* __restrict__ qf,   // [BT*64][256]
    const float* __restrict__ Wi,   // [256][32]
    const float* __restrict__ bi,   // [32]
    const float* __restrict__ Wm,   // [256][16]
    const float* __restrict__ bm,   // [16]
    short* __restrict__ qtabB)      // [BT][3][2][64][8] bf16
{
    int idx = blockIdx.x * 256 + threadIdx.x;   // 8*64*48 = 24576
    int btq = idx / CD;            // bt*64 + q
    int d   = idx - btq * CD;      // 0..47
    int bt  = btq >> 6;
    int q   = btq & 63;
    const float* __restrict__ qrow = qf + btq * QD;
    float a;
    if (d < ID) {
        a = bi[d];
        #pragma unroll 8
        for (int k = 0; k < QD; ++k) a = fmaf(qrow[k], Wi[k*ID + d], a);
    } else {
        int dm = d - ID;
        a = bm[dm];
        #pragma unroll 8
        for (int k = 0; k < QD; ++k) a = fmaf(qrow[k], Wm[k*MD + dm], a);
    }
    int nt = d >> 4, c = d & 15;
    int kt = q >> 5, kk = q & 31;
    int lane = ((kk >> 3) << 4) | c;
    int j    = kk & 7;
    qtabB[((((bt*3 + nt)*2 + kt) << 6) + lane) * 8 + j] = f2bf(a);
}

// Kernel B: per block, 256 locations. pooled = P @ Q via MFMA (psum = ones column).
__global__ __launch_bounds__(256) void entity_kernel(
    const float* __restrict__ ia,     // [BT*VHW][32]
    const float* __restrict__ mc,     // [BT*VHW][16]
    const float* __restrict__ ap,     // [BT*VHW][65]
    const int*   __restrict__ aq,     // [BT*VHW]
    const short* __restrict__ qtabB,  // [BT][3][2][64][8] bf16
    float* __restrict__ out_id,
    float* __restrict__ out_inst,     // [BT*VHW][32]
    float* __restrict__ out_mot)      // [BT*VHW][16]
{
    __shared__ short ap_s[256 * PITCH];   // 36,864 B bf16 probs
    __shared__ float bg_s[256];
    __shared__ float psum_s[256];
    __shared__ float scale_s[256];

    const int  t    = threadIdx.x;
    const int  lane = t & 63;
    const int  w    = t >> 6;             // wave id 0..3
    const int  bt   = blockIdx.x >> 8;    // uniform
    const long base = (long)blockIdx.x << 8;

    // ---- stage ap tile (coalesced float4 span) + convert to bf16 in LDS ----
    {
        const float4* __restrict__ src = (const float4*)(ap + base * APW); // 66,560B/block, 16B aligned
        #pragma unroll
        for (int k = 0; k < 17; ++k) {
            int f = t + 256 * k;
            if (f < (256 * APW) / 4) {
                float4 v = src[f];
                int e0 = 4 * f;
                #pragma unroll
                for (int e = 0; e < 4; ++e) {
                    int   ix  = e0 + e;
                    int   loc = ix / APW;            // magic-mul div
                    int   col = ix - loc * APW;
                    float val = (&v.x)[e];
                    if (col == 0) bg_s[loc] = val;
                    else          ap_s[loc * PITCH + (col - 1)] = f2bf(val);
                }
            }
        }
    }

    // ---- B fragments: coalesced 16B loads from pre-packed table ----
    bf16x8 Bf[3][2];
    {
        const bf16x8* __restrict__ qb = (const bf16x8*)(qtabB + bt * (3*2*64*8));
        #pragma unroll
        for (int nt = 0; nt < 3; ++nt)
            #pragma unroll
            for (int kt = 0; kt < 2; ++kt)
                Bf[nt][kt] = qb[(nt*2 + kt) * 64 + lane];
    }
    bf16x8 Bones;
    {
        short one = ((lane & 15) == 0) ? (short)0x3F80 : (short)0;  // bf16 1.0
        #pragma unroll
        for (int j = 0; j < 8; ++j) Bones[j] = one;
    }

    __syncthreads();

    // ---- MFMA: 4 M-tiles x (3 N-tiles + psum) x 2 K-steps ----
    f32x4 acc[4][3];
    f32x4 accP[4];
    #pragma unroll
    for (int m = 0; m < 4; ++m) {
        accP[m] = (f32x4){0.f, 0.f, 0.f, 0.f};
        #pragma unroll
        for (int n = 0; n < 3; ++n) acc[m][n] = (f32x4){0.f, 0.f, 0.f, 0.f};
    }
    #pragma unroll
    for (int kt = 0; kt < 2; ++kt) {
        #pragma unroll
        for (int m = 0; m < 4; ++m) {
            // A-frag: row = wave*64 + m*16 + (lane&15), k = kt*32 + (lane>>4)*8 + j
            const bf16x8 A = *(const bf16x8*)(ap_s +
                (w*64 + m*16 + (lane & 15)) * PITCH + kt*32 + ((lane >> 4) << 3));
            acc[m][0] = __builtin_amdgcn_mfma_f32_16x16x32_bf16(A, Bf[0][kt], acc[m][0], 0, 0, 0);
            acc[m][1] = __builtin_amdgcn_mfma_f32_16x16x32_bf16(A, Bf[1][kt], acc[m][1], 0, 0, 0);
            acc[m][2] = __builtin_amdgcn_mfma_f32_16x16x32_bf16(A, Bf[2][kt], acc[m][2], 0, 0, 0);
            accP[m]   = __builtin_amdgcn_mfma_f32_16x16x32_bf16(A, Bones,     accP[m],   0, 0, 0);
        }
    }

    // ---- psum broadcast: C layout col=lane&15, row=(lane>>4)*4+reg ----
    if ((lane & 15) == 0) {
        int g = lane >> 4;
        #pragma unroll
        for (int m = 0; m < 4; ++m)
            #pragma unroll
            for (int r = 0; r < 4; ++r)
                psum_s[w*64 + m*16 + g*4 + r] = accP[m][r];
    }
    __syncthreads();
    scale_s[t] = (1.0f - bg_s[t]) / fmaxf(psum_s[t], 1e-6f);
    __syncthreads();

    // ---- epilogue: frag-indexed residual add, 4x64B segments per store ----
    const int c = lane & 15, g = lane >> 4;
    #pragma unroll
    for (int m = 0; m < 4; ++m) {
        const int lrow = w*64 + m*16 + g*4;
        #pragma unroll
        for (int r = 0; r < 4; ++r) {
            const long  loc = base + lrow + r;
            const float s   = scale_s[lrow + r];
            out_inst[loc*ID + c]      = ia[loc*ID + c]      + s * acc[m][0][r];
            out_inst[loc*ID + 16 + c] = ia[loc*ID + 16 + c] + s * acc[m][1][r];
            out_mot [loc*MD + c]      = mc[loc*MD + c]      + s * acc[m][2][r];
        }
    }
    out_id[base + t] = (float)aq[base + t];
}

extern "C" void kernel_launch(void* const* d_in, const int* in_sizes, int n_in,
                              void* d_out, int out_size, void* d_ws, size_t ws_size,
                              hipStream_t stream) {
    const float* ia = (const float*)d_in[0];
    const float* mc = (const float*)d_in[1];
    const float* qf = (const float*)d_in[2];
    const float* ap = (const float*)d_in[3];
    const int*   aq = (const int*)  d_in[4];
    const float* Wi = (const float*)d_in[5];
    const float* bi = (const float*)d_in[6];
    const float* Wm = (const float*)d_in[7];
    const float* bm = (const float*)d_in[8];

    short* qtabB = (short*)d_ws;                       // 8*3*2*64*8*2 = 49,152 B

    float* out_id   = (float*)d_out;
    float* out_inst = out_id + (long)BT * VHW;
    float* out_mot  = out_inst + (long)BT * VHW * ID;

    qproj_kernel<<<(BT * NQn * CD) / 256, 256, 0, stream>>>(qf, Wi, bi, Wm, bm, qtabB);
    entity_kernel<<<(BT * VHW) / 256, 256, 0, stream>>>(ia, mc, ap, aq, qtabB,
                                                        out_id, out_inst, out_mot);
}